// Round 4
// baseline (69.562 us; speedup 1.0000x reference)
//
#include <hip/hip_runtime.h>
#include <math.h>

// ---------------------------------------------------------------------------
// StageALoss (FCOS-like), fully fused single kernel.
//
// R3 -> R4: (a) fin_k folded into level_k via threadfence-reduction ("last
// block done" agent-scope counter) -- removes one kernel node and the 1-block
// kernel's serial cold-read tail; counter armed by a 4-byte memset node.
// (b) both per-thread d0 stripe loads issued before any dependent math (2x
// memory-level parallelism on the ~80% of waves that skip ltrb channels).
// ---------------------------------------------------------------------------

#define NBLK 1408   // lvl0: 1024 (8/batch), lvl1: 256 (2/batch), lvl2: 128 (1/batch)
#define N_PB 384    // 3 levels * 128 batches

__device__ __forceinline__ float rcpf(float x) { return __builtin_amdgcn_rcpf(x); }

__device__ __forceinline__ float logsigf(float x) {
    return fminf(x, 0.f) - log1pf(expf(-fabsf(x)));
}

// agent(device)-scope loads for cross-XCD-visible partials (G16)
__device__ __forceinline__ float ld_f32(const float* p) {
    return __hip_atomic_load(p, __ATOMIC_RELAXED, __HIP_MEMORY_SCOPE_AGENT);
}
__device__ __forceinline__ int ld_i32(const int* p) {
    return __hip_atomic_load(p, __ATOMIC_RELAXED, __HIP_MEMORY_SCOPE_AGENT);
}
__device__ __forceinline__ unsigned long long ld_u64(const unsigned long long* p) {
    return __hip_atomic_load(p, __ATOMIC_RELAXED, __HIP_MEMORY_SCOPE_AGENT);
}

// Focal + (conditional) CIoU for 4 consecutive-x locations; d0 preloaded.
__device__ __forceinline__ void proc4(
    const float* __restrict__ det, size_t c0base, int loc, int Wm1, int log2W,
    size_t HW, float stride, float x1, float y1, float x2, float y2,
    float bcx, float bcy, float4 d0,
    float& conf, float& ciou, int& np, unsigned long long& pk)
{
    const int xi = loc & Wm1;
    const int yi = loc >> log2W;
    const float cy = ((float)yi + 0.5f) * stride;

    float cxs[4]; bool inb[4]; bool anyb = false;
    #pragma unroll
    for (int j = 0; j < 4; ++j) {
        cxs[j] = ((float)(xi + j) + 0.5f) * stride;
        inb[j] = (cxs[j] > x1) & (cxs[j] < x2) & (cy > y1) & (cy < y2);
        anyb |= inb[j];
    }

    const float zs[4] = { d0.x, d0.y, d0.z, d0.w };
    #pragma unroll
    for (int j = 0; j < 4; ++j) {
        const float z  = zs[j];
        const float e  = __expf(-fabsf(z));            // (0, 1]
        const float ce = fmaxf(z, 0.f) - (inb[j] ? z : 0.f) + __logf(1.f + e);
        const float inv = rcpf(1.f + e);
        const float p  = (z >= 0.f) ? inv : e * inv;   // sigmoid(z)
        const float pt = inb[j] ? p : 1.f - p;
        const float at = inb[j] ? 0.25f : 0.75f;
        const float om = 1.f - pt;
        conf += at * om * om * ce;
    }

    if (__any(anyb)) {  // wave-uniform: ltrb channels only near boxes
        const float4 d1 = *(const float4*)(det + c0base + HW + (size_t)loc);
        const float4 d2 = *(const float4*)(det + c0base + 2 * HW + (size_t)loc);
        const float4 d3 = *(const float4*)(det + c0base + 3 * HW + (size_t)loc);
        const float4 d4 = *(const float4*)(det + c0base + 4 * HW + (size_t)loc);
        const float ls[4] = { d1.x, d1.y, d1.z, d1.w };
        const float ts[4] = { d2.x, d2.y, d2.z, d2.w };
        const float rs[4] = { d3.x, d3.y, d3.z, d3.w };
        const float bs[4] = { d4.x, d4.y, d4.z, d4.w };
        #pragma unroll
        for (int j = 0; j < 4; ++j) {
            if (!inb[j]) continue;
            const float cx = cxs[j];
            const float pl  = __expf(fminf(fmaxf(ls[j], -6.f), 6.f)) * stride;
            const float pt_ = __expf(fminf(fmaxf(ts[j], -6.f), 6.f)) * stride;
            const float pr  = __expf(fminf(fmaxf(rs[j], -6.f), 6.f)) * stride;
            const float pb  = __expf(fminf(fmaxf(bs[j], -6.f), 6.f)) * stride;
            const float gl  = cx - x1, gtl = cy - y1, gr = x2 - cx, gb = y2 - cy;
            const float pw = pl + pr, ph = pt_ + pb;
            const float gw = gl + gr, gh = gtl + gb;
            const float iw = fmaxf(fminf(pl, gl) + fminf(pr, gr), 0.f);
            const float ih = fmaxf(fminf(pt_, gtl) + fminf(pb, gb), 0.f);
            const float inter = iw * ih;
            const float uni   = pw * ph + gw * gh - inter + 1e-6f;
            const float iou   = inter * rcpf(uni);
            const float cw_ = fmaxf(pl, gl) + fmaxf(pr, gr);
            const float ch_ = fmaxf(pt_, gtl) + fmaxf(pb, gb);
            const float c2  = cw_ * cw_ + ch_ * ch_ + 1e-6f;
            const float dcx = 0.5f * (pr - pl) - 0.5f * (gr - gl);
            const float dcy = 0.5f * (pb - pt_) - 0.5f * (gb - gtl);
            const float rho2 = dcx * dcx + dcy * dcy;
            const float dv = atanf(gw * rcpf(gh + 1e-6f)) - atanf(pw * rcpf(ph + 1e-6f));
            const float v  = (4.f / (float)(M_PI * M_PI)) * dv * dv;
            const float alpha = v * rcpf(1.f - iou + v + 1e-6f);
            ciou += 1.f - iou + rho2 * rcpf(c2) + alpha * v;
            ++np;
            const float ddx = cx - bcx, ddy = cy - bcy;
            const float dist2 = ddx * ddx + ddy * ddy;
            const unsigned long long cand =
                ((unsigned long long)__float_as_uint(dist2) << 32) | (unsigned)(loc + j);
            pk = cand < pk ? cand : pk;  // min -> first-index tie-break (argmin)
        }
    }
}

__global__ __launch_bounds__(256) void fused_k(
    const float* __restrict__ det8, const float* __restrict__ det16, const float* __restrict__ det32,
    const float* __restrict__ q8, const float* __restrict__ q16, const float* __restrict__ q32,
    const float* __restrict__ gtb, const float* __restrict__ gtq,
    unsigned long long* __restrict__ pk_part, float* __restrict__ conf_part,
    float* __restrict__ ciou_part, int* __restrict__ np_part,
    unsigned int* __restrict__ counter,
    float* __restrict__ out)
{
    const int tid = (int)threadIdx.x;
    const int bid = (int)blockIdx.x;

    int b, base, log2W, nvec;
    const float* det; float stride; float inv_denom; size_t HW;
    if (bid < 1024) {
        b = bid >> 3; base = (bid & 7) * 2048; nvec = 2;
        det = det8;  stride = 8.f;  log2W = 7; HW = 16384; inv_denom = 1.f / 2097152.f;
    } else if (bid < 1280) {
        const int rel = bid - 1024;
        b = rel >> 1; base = (rel & 1) * 2048; nvec = 2;
        det = det16; stride = 16.f; log2W = 6; HW = 4096; inv_denom = 1.f / 524288.f;
    } else {
        b = bid - 1280; base = 0; nvec = 1;
        det = det32; stride = 32.f; log2W = 5; HW = 1024; inv_denom = 1.f / 131072.f;
    }

    float conf = 0.f, ciou = 0.f; int np = 0;
    unsigned long long pk = ~0ULL;

    const float x1 = gtb[b * 4 + 0];
    if (x1 >= 0.f) {  // invalid batch contributes exactly 0 everywhere
        const float y1 = gtb[b * 4 + 1];
        const float x2 = gtb[b * 4 + 2];
        const float y2 = gtb[b * 4 + 3];
        const float bcx = 0.5f * (x1 + x2);
        const float bcy = 0.5f * (y1 + y2);
        const size_t c0base = (size_t)(b * 5) * HW;
        const int Wm1 = (1 << log2W) - 1;
        const int locA = base + (tid << 2);

        // issue both stripe d0 loads before any dependent math (2x MLP)
        const float4 dA = *(const float4*)(det + c0base + (size_t)locA);
        float4 dB;
        if (nvec == 2) dB = *(const float4*)(det + c0base + (size_t)(locA + 1024));

        proc4(det, c0base, locA, Wm1, log2W, HW, stride, x1, y1, x2, y2, bcx, bcy,
              dA, conf, ciou, np, pk);
        if (nvec == 2)
            proc4(det, c0base, locA + 1024, Wm1, log2W, HW, stride, x1, y1, x2, y2, bcx, bcy,
                  dB, conf, ciou, np, pk);
        conf *= inv_denom;
    }

    // wave (64-lane) shuffle reduction
    #pragma unroll
    for (int off = 32; off > 0; off >>= 1) {
        conf += __shfl_down(conf, off);
        ciou += __shfl_down(ciou, off);
        np   += __shfl_down(np, off);
        unsigned long long o = __shfl_down(pk, off);
        pk = o < pk ? o : pk;
    }

    // cross-wave via LDS, single partial store per block, then arrive
    __shared__ float s_conf[4], s_ciou[4];
    __shared__ int   s_np[4];
    __shared__ unsigned long long s_pk[4];
    __shared__ int s_last;
    const int wid = tid >> 6;
    if ((tid & 63) == 0) {
        s_conf[wid] = conf; s_ciou[wid] = ciou; s_np[wid] = np; s_pk[wid] = pk;
    }
    __syncthreads();
    if (tid == 0) {
        conf_part[bid] = s_conf[0] + s_conf[1] + s_conf[2] + s_conf[3];
        ciou_part[bid] = s_ciou[0] + s_ciou[1] + s_ciou[2] + s_ciou[3];
        np_part[bid]   = s_np[0] + s_np[1] + s_np[2] + s_np[3];
        unsigned long long mn = s_pk[0];
        mn = s_pk[1] < mn ? s_pk[1] : mn;
        mn = s_pk[2] < mn ? s_pk[2] : mn;
        mn = s_pk[3] < mn ? s_pk[3] : mn;
        pk_part[bid] = mn;
        __threadfence();  // make partials device-visible before arrival
        const unsigned int old = __hip_atomic_fetch_add(
            counter, 1u, __ATOMIC_ACQ_REL, __HIP_MEMORY_SCOPE_AGENT);
        s_last = (old == (unsigned)(NBLK - 1)) ? 1 : 0;
    }
    __syncthreads();
    if (!s_last) return;

    // ---------------- finalization by the last-arriving block ----------------
    __shared__ float fc[256], fb[256], fq[256];
    __shared__ int   fn[256];

    float cacc = 0.f;
    for (int j = tid; j < NBLK; j += 256) cacc += ld_f32(conf_part + j);

    float bbacc = 0.f, qlacc = 0.f; int nacc = 0;
    for (int s = tid; s < N_PB; s += 256) {
        const int lvl = s >> 7, bb_ = s & 127;
        int first, cnt;
        if (lvl == 0)      { first = bb_ * 8;        cnt = 8; }
        else if (lvl == 1) { first = 1024 + bb_ * 2; cnt = 2; }
        else               { first = 1280 + bb_;     cnt = 1; }
        float ci = 0.f; int nps = 0; unsigned long long mn = ~0ULL;
        for (int k = 0; k < cnt; ++k) {
            ci  += ld_f32(ciou_part + first + k);
            nps += ld_i32(np_part + first + k);
            const unsigned long long p = ld_u64(pk_part + first + k);
            mn = p < mn ? p : mn;
        }
        if (nps > 0) {
            bbacc += ci / (float)nps;  // ciou_mean
            const unsigned idx = (unsigned)(mn & 0xffffffffULL);
            const float* q; int log2HW2;
            if (lvl == 0)      { q = q8;  log2HW2 = 14; }
            else if (lvl == 1) { q = q16; log2HW2 = 12; }
            else               { q = q32; log2HW2 = 10; }
            float sacc = 0.f;
            #pragma unroll
            for (int c = 0; c < 4; ++c) {
                const float best = q[((size_t)(bb_ * 4 + c) << log2HW2) + idx];
                const float qt = fminf(fmaxf(gtq[bb_ * 4 + c], 0.05f), 0.95f);
                sacc -= qt * logsigf(best) + (1.f - qt) * logsigf(-best);
            }
            qlacc += 0.25f * sacc;  // bce.mean over C_Q=4
            nacc  += 1;             // has_pos
        }
    }

    fc[tid] = cacc; fb[tid] = bbacc; fq[tid] = qlacc; fn[tid] = nacc;
    __syncthreads();
    #pragma unroll
    for (int off = 128; off > 0; off >>= 1) {
        if (tid < off) {
            fc[tid] += fc[tid + off]; fb[tid] += fb[tid + off];
            fq[tid] += fq[tid + off]; fn[tid] += fn[tid + off];
        }
        __syncthreads();
    }
    if (tid == 0) {
        const float conf_t = fc[0];
        const int ntot = fn[0];
        const float denom = fmaxf((float)ntot, 1.f);
        const float tb = (ntot > 0) ? fb[0] / denom : fb[0];
        const float tq = (ntot > 0) ? fq[0] / denom : fq[0];
        out[0] = conf_t + 5.f * tb + 0.05f * tq;
        out[1] = conf_t;
        out[2] = tb;
        out[3] = tq;
    }
}

extern "C" void kernel_launch(void* const* d_in, const int* in_sizes, int n_in,
                              void* d_out, int out_size, void* d_ws, size_t ws_size,
                              hipStream_t stream) {
    const float* det8  = (const float*)d_in[0];
    const float* det16 = (const float*)d_in[1];
    const float* det32 = (const float*)d_in[2];
    const float* q8    = (const float*)d_in[3];
    const float* q16   = (const float*)d_in[4];
    const float* q32   = (const float*)d_in[5];
    const float* gtb   = (const float*)d_in[6];
    const float* gtq   = (const float*)d_in[7];
    float* out = (float*)d_out;

    // workspace layout (28164 bytes): u64 first for alignment
    unsigned long long* pk_part = (unsigned long long*)d_ws;        // 1408*8 = 11264
    float* conf_part = (float*)((char*)d_ws + 11264);               // 1408*4 =  5632
    float* ciou_part = (float*)((char*)d_ws + 16896);               // 1408*4 =  5632
    int*   np_part   = (int*)((char*)d_ws + 22528);                 // 1408*4 =  5632
    unsigned int* counter = (unsigned int*)((char*)d_ws + 28160);   // 4

    hipMemsetAsync(counter, 0, 4, stream);  // arm the arrival counter (graph-capturable)
    hipLaunchKernelGGL(fused_k, dim3(NBLK), dim3(256), 0, stream,
                       det8, det16, det32, q8, q16, q32, gtb, gtq,
                       pk_part, conf_part, ciou_part, np_part, counter, out);
}

// Round 5
// 21.411 us; speedup vs baseline: 3.2489x; 3.2489x over previous
//
#include <hip/hip_runtime.h>
#include <math.h>

// ---------------------------------------------------------------------------
// StageALoss (FCOS-like): conf focal over all locations, CIoU over in-box,
// quality BCE at argmin-dist location per (level,batch).
//
// R4 -> R5: REVERT the fused last-block-done design (69.6us): 1408 device-
// scope fences + same-address atomics stall ~80us on multi-XCD CDNA. Back to
// the two-kernel R3 structure (22us), plus: 768 blocks with 4 vec-stripes per
// thread, all 4 d0 float4 loads issued up-front (4x MLP, half the waves);
// fast exp/log in fin_k's BCE tail. No atomics, no fences anywhere.
// ---------------------------------------------------------------------------

#define NBLK 768    // lvl0: 512 (4/batch), lvl1: 128 (1/batch), lvl2: 128 (1/batch)
#define N_PB 384    // 3 levels * 128 batches

__device__ __forceinline__ float rcpf(float x) { return __builtin_amdgcn_rcpf(x); }

__device__ __forceinline__ float logsigf(float x) {
    return fminf(x, 0.f) - __logf(1.f + __expf(-fabsf(x)));
}

// Focal + (conditional) CIoU for 4 consecutive-x locations; d0 preloaded.
__device__ __forceinline__ void proc4(
    const float* __restrict__ det, size_t c0base, int loc, int Wm1, int log2W,
    size_t HW, float stride, float x1, float y1, float x2, float y2,
    float bcx, float bcy, float4 d0,
    float& conf, float& ciou, int& np, unsigned long long& pk)
{
    const int xi = loc & Wm1;
    const int yi = loc >> log2W;
    const float cy = ((float)yi + 0.5f) * stride;

    float cxs[4]; bool inb[4]; bool anyb = false;
    #pragma unroll
    for (int j = 0; j < 4; ++j) {
        cxs[j] = ((float)(xi + j) + 0.5f) * stride;
        inb[j] = (cxs[j] > x1) & (cxs[j] < x2) & (cy > y1) & (cy < y2);
        anyb |= inb[j];
    }

    const float zs[4] = { d0.x, d0.y, d0.z, d0.w };
    #pragma unroll
    for (int j = 0; j < 4; ++j) {
        const float z  = zs[j];
        const float e  = __expf(-fabsf(z));            // (0, 1]
        const float ce = fmaxf(z, 0.f) - (inb[j] ? z : 0.f) + __logf(1.f + e);
        const float inv = rcpf(1.f + e);
        const float p  = (z >= 0.f) ? inv : e * inv;   // sigmoid(z)
        const float pt = inb[j] ? p : 1.f - p;
        const float at = inb[j] ? 0.25f : 0.75f;
        const float om = 1.f - pt;
        conf += at * om * om * ce;
    }

    if (__any(anyb)) {  // wave-uniform: ltrb channels only near boxes
        const float4 d1 = *(const float4*)(det + c0base + HW + (size_t)loc);
        const float4 d2 = *(const float4*)(det + c0base + 2 * HW + (size_t)loc);
        const float4 d3 = *(const float4*)(det + c0base + 3 * HW + (size_t)loc);
        const float4 d4 = *(const float4*)(det + c0base + 4 * HW + (size_t)loc);
        const float ls[4] = { d1.x, d1.y, d1.z, d1.w };
        const float ts[4] = { d2.x, d2.y, d2.z, d2.w };
        const float rs[4] = { d3.x, d3.y, d3.z, d3.w };
        const float bs[4] = { d4.x, d4.y, d4.z, d4.w };
        #pragma unroll
        for (int j = 0; j < 4; ++j) {
            if (!inb[j]) continue;
            const float cx = cxs[j];
            const float pl  = __expf(fminf(fmaxf(ls[j], -6.f), 6.f)) * stride;
            const float pt_ = __expf(fminf(fmaxf(ts[j], -6.f), 6.f)) * stride;
            const float pr  = __expf(fminf(fmaxf(rs[j], -6.f), 6.f)) * stride;
            const float pb  = __expf(fminf(fmaxf(bs[j], -6.f), 6.f)) * stride;
            const float gl  = cx - x1, gtl = cy - y1, gr = x2 - cx, gb = y2 - cy;
            const float pw = pl + pr, ph = pt_ + pb;
            const float gw = gl + gr, gh = gtl + gb;
            const float iw = fmaxf(fminf(pl, gl) + fminf(pr, gr), 0.f);
            const float ih = fmaxf(fminf(pt_, gtl) + fminf(pb, gb), 0.f);
            const float inter = iw * ih;
            const float uni   = pw * ph + gw * gh - inter + 1e-6f;
            const float iou   = inter * rcpf(uni);
            const float cw_ = fmaxf(pl, gl) + fmaxf(pr, gr);
            const float ch_ = fmaxf(pt_, gtl) + fmaxf(pb, gb);
            const float c2  = cw_ * cw_ + ch_ * ch_ + 1e-6f;
            const float dcx = 0.5f * (pr - pl) - 0.5f * (gr - gl);
            const float dcy = 0.5f * (pb - pt_) - 0.5f * (gb - gtl);
            const float rho2 = dcx * dcx + dcy * dcy;
            const float dv = atanf(gw * rcpf(gh + 1e-6f)) - atanf(pw * rcpf(ph + 1e-6f));
            const float v  = (4.f / (float)(M_PI * M_PI)) * dv * dv;
            const float alpha = v * rcpf(1.f - iou + v + 1e-6f);
            ciou += 1.f - iou + rho2 * rcpf(c2) + alpha * v;
            ++np;
            const float ddx = cx - bcx, ddy = cy - bcy;
            const float dist2 = ddx * ddx + ddy * ddy;
            const unsigned long long cand =
                ((unsigned long long)__float_as_uint(dist2) << 32) | (unsigned)(loc + j);
            pk = cand < pk ? cand : pk;  // min -> first-index tie-break (argmin)
        }
    }
}

// Block map (256 threads, 4 locs per vec, stripes of 1024 locs):
//   bid < 512 : lvl0, b = bid>>2, base = (bid&3)*4096, 4 stripes
//   512..639  : lvl1, b = bid-512, base = 0,           4 stripes (whole 4096)
//   640..767  : lvl2, b = bid-640, base = 0,           1 stripe  (whole 1024)
__global__ __launch_bounds__(256) void level_k(
    const float* __restrict__ det8, const float* __restrict__ det16, const float* __restrict__ det32,
    const float* __restrict__ gtb,
    unsigned long long* __restrict__ pk_part, float* __restrict__ conf_part,
    float* __restrict__ ciou_part, int* __restrict__ np_part)
{
    const int tid = (int)threadIdx.x;
    const int bid = (int)blockIdx.x;

    int b, base, log2W, nstripe;
    const float* det; float stride; float inv_denom; size_t HW;
    if (bid < 512) {
        b = bid >> 2; base = (bid & 3) * 4096; nstripe = 4;
        det = det8;  stride = 8.f;  log2W = 7; HW = 16384; inv_denom = 1.f / 2097152.f;
    } else if (bid < 640) {
        b = bid - 512; base = 0; nstripe = 4;
        det = det16; stride = 16.f; log2W = 6; HW = 4096; inv_denom = 1.f / 524288.f;
    } else {
        b = bid - 640; base = 0; nstripe = 1;
        det = det32; stride = 32.f; log2W = 5; HW = 1024; inv_denom = 1.f / 131072.f;
    }

    float conf = 0.f, ciou = 0.f; int np = 0;
    unsigned long long pk = ~0ULL;

    const float x1 = gtb[b * 4 + 0];
    if (x1 >= 0.f) {  // invalid batch contributes exactly 0 everywhere
        const float y1 = gtb[b * 4 + 1];
        const float x2 = gtb[b * 4 + 2];
        const float y2 = gtb[b * 4 + 3];
        const float bcx = 0.5f * (x1 + x2);
        const float bcy = 0.5f * (y1 + y2);
        const size_t c0base = (size_t)(b * 5) * HW;
        const int Wm1 = (1 << log2W) - 1;
        const int loc0 = base + (tid << 2);

        if (nstripe == 4) {
            // issue all 4 d0 loads before any dependent math (4x MLP)
            const float4 dA = *(const float4*)(det + c0base + (size_t)loc0);
            const float4 dB = *(const float4*)(det + c0base + (size_t)(loc0 + 1024));
            const float4 dC = *(const float4*)(det + c0base + (size_t)(loc0 + 2048));
            const float4 dD = *(const float4*)(det + c0base + (size_t)(loc0 + 3072));
            proc4(det, c0base, loc0,        Wm1, log2W, HW, stride, x1, y1, x2, y2, bcx, bcy, dA, conf, ciou, np, pk);
            proc4(det, c0base, loc0 + 1024, Wm1, log2W, HW, stride, x1, y1, x2, y2, bcx, bcy, dB, conf, ciou, np, pk);
            proc4(det, c0base, loc0 + 2048, Wm1, log2W, HW, stride, x1, y1, x2, y2, bcx, bcy, dC, conf, ciou, np, pk);
            proc4(det, c0base, loc0 + 3072, Wm1, log2W, HW, stride, x1, y1, x2, y2, bcx, bcy, dD, conf, ciou, np, pk);
        } else {
            const float4 dA = *(const float4*)(det + c0base + (size_t)loc0);
            proc4(det, c0base, loc0, Wm1, log2W, HW, stride, x1, y1, x2, y2, bcx, bcy, dA, conf, ciou, np, pk);
        }
        conf *= inv_denom;
    }

    // wave (64-lane) shuffle reduction
    #pragma unroll
    for (int off = 32; off > 0; off >>= 1) {
        conf += __shfl_down(conf, off);
        ciou += __shfl_down(ciou, off);
        np   += __shfl_down(np, off);
        unsigned long long o = __shfl_down(pk, off);
        pk = o < pk ? o : pk;
    }

    // cross-wave via LDS, single plain store per block (no atomics)
    __shared__ float s_conf[4], s_ciou[4];
    __shared__ int   s_np[4];
    __shared__ unsigned long long s_pk[4];
    const int wid = tid >> 6;
    if ((tid & 63) == 0) {
        s_conf[wid] = conf; s_ciou[wid] = ciou; s_np[wid] = np; s_pk[wid] = pk;
    }
    __syncthreads();
    if (tid == 0) {
        conf_part[bid] = s_conf[0] + s_conf[1] + s_conf[2] + s_conf[3];
        ciou_part[bid] = s_ciou[0] + s_ciou[1] + s_ciou[2] + s_ciou[3];
        np_part[bid]   = s_np[0] + s_np[1] + s_np[2] + s_np[3];
        unsigned long long mn = s_pk[0];
        mn = s_pk[1] < mn ? s_pk[1] : mn;
        mn = s_pk[2] < mn ? s_pk[2] : mn;
        mn = s_pk[3] < mn ? s_pk[3] : mn;
        pk_part[bid] = mn;
    }
}

__global__ __launch_bounds__(512) void fin_k(
    const float* __restrict__ q8, const float* __restrict__ q16, const float* __restrict__ q32,
    const float* __restrict__ gtq,
    const unsigned long long* __restrict__ pk_part, const float* __restrict__ conf_part,
    const float* __restrict__ ciou_part, const int* __restrict__ np_part,
    float* __restrict__ out)
{
    __shared__ float sc[512];
    __shared__ float sb[512];
    __shared__ float sq[512];
    __shared__ int   sn[512];
    const int i = threadIdx.x;

    float cp = 0.f;
    for (int j = i; j < NBLK; j += 512) cp += conf_part[j];

    float bb = 0.f, ql = 0.f; int n = 0;
    if (i < N_PB) {
        const int lvl = i >> 7, b = i & 127;
        // static block->slot mapping
        int first, cnt;
        if (lvl == 0)      { first = b * 4;   cnt = 4; }
        else if (lvl == 1) { first = 512 + b; cnt = 1; }
        else               { first = 640 + b; cnt = 1; }
        float ci = 0.f; int np = 0; unsigned long long mn = ~0ULL;
        for (int k = 0; k < cnt; ++k) {
            ci += ciou_part[first + k];
            np += np_part[first + k];
            const unsigned long long p = pk_part[first + k];
            mn = p < mn ? p : mn;
        }
        if (np > 0) {
            bb = ci / (float)np;  // ciou_mean
            const unsigned idx = (unsigned)(mn & 0xffffffffULL);
            const float* q; int log2HW;
            if (lvl == 0)      { q = q8;  log2HW = 14; }
            else if (lvl == 1) { q = q16; log2HW = 12; }
            else               { q = q32; log2HW = 10; }
            float s = 0.f;
            #pragma unroll
            for (int c = 0; c < 4; ++c) {
                const float best = q[((size_t)(b * 4 + c) << log2HW) + idx];
                const float qt = fminf(fmaxf(gtq[b * 4 + c], 0.05f), 0.95f);
                s -= qt * logsigf(best) + (1.f - qt) * logsigf(-best);
            }
            ql = 0.25f * s;  // bce.mean over C_Q=4
            n = 1;           // has_pos
        }
    }
    sc[i] = cp; sb[i] = bb; sq[i] = ql; sn[i] = n;
    __syncthreads();
    #pragma unroll
    for (int off = 256; off > 0; off >>= 1) {
        if (i < off) { sc[i] += sc[i + off]; sb[i] += sb[i + off]; sq[i] += sq[i + off]; sn[i] += sn[i + off]; }
        __syncthreads();
    }
    if (i == 0) {
        const float conf = sc[0];
        const int ntot = sn[0];
        const float denom = fmaxf((float)ntot, 1.f);
        const float tb = (ntot > 0) ? sb[0] / denom : sb[0];
        const float tq = (ntot > 0) ? sq[0] / denom : sq[0];
        out[0] = conf + 5.f * tb + 0.05f * tq;
        out[1] = conf;
        out[2] = tb;
        out[3] = tq;
    }
}

extern "C" void kernel_launch(void* const* d_in, const int* in_sizes, int n_in,
                              void* d_out, int out_size, void* d_ws, size_t ws_size,
                              hipStream_t stream) {
    const float* det8  = (const float*)d_in[0];
    const float* det16 = (const float*)d_in[1];
    const float* det32 = (const float*)d_in[2];
    const float* q8    = (const float*)d_in[3];
    const float* q16   = (const float*)d_in[4];
    const float* q32   = (const float*)d_in[5];
    const float* gtb   = (const float*)d_in[6];
    const float* gtq   = (const float*)d_in[7];
    float* out = (float*)d_out;

    // workspace layout (15360 bytes): u64 first for alignment
    unsigned long long* pk_part = (unsigned long long*)d_ws;        // 768*8 = 6144
    float* conf_part = (float*)((char*)d_ws + 6144);                // 768*4 = 3072
    float* ciou_part = (float*)((char*)d_ws + 9216);                // 768*4 = 3072
    int*   np_part   = (int*)((char*)d_ws + 12288);                 // 768*4 = 3072

    hipLaunchKernelGGL(level_k, dim3(NBLK), dim3(256), 0, stream,
                       det8, det16, det32, gtb, pk_part, conf_part, ciou_part, np_part);
    hipLaunchKernelGGL(fin_k, dim3(1), dim3(512), 0, stream,
                       q8, q16, q32, gtq, pk_part, conf_part, ciou_part, np_part, out);
}

// Round 6
// 20.798 us; speedup vs baseline: 3.3446x; 1.0295x over previous
//
#include <hip/hip_runtime.h>
#include <math.h>

// ---------------------------------------------------------------------------
// StageALoss (FCOS-like): conf focal over all locations, CIoU over in-box,
// quality BCE at argmin-dist location per (level,batch).
//
// R5 -> R6: lvl1/lvl2 blocks fully own their (level,batch) slot, so their
// ciou_mean + argmin qual-BCE gather + has_pos are finalized inside level_k
// (overlapped with other blocks' streaming). fin_k now: 768 conf partials +
// 128 lvl0 slot combines (4-way) + flat sum of 256 precomputed contributions,
// with a barrier-light wave-shuffle epilogue. Two kernels, no atomics, no
// fences (R4 showed device-scope sync costs ~50us on multi-XCD CDNA).
// ---------------------------------------------------------------------------

#define NBLK 768    // lvl0: 512 (4/batch), lvl1: 128 (1/batch), lvl2: 128 (1/batch)

__device__ __forceinline__ float rcpf(float x) { return __builtin_amdgcn_rcpf(x); }

__device__ __forceinline__ float logsigf(float x) {
    return fminf(x, 0.f) - __logf(1.f + __expf(-fabsf(x)));
}

// Focal + (conditional) CIoU for 4 consecutive-x locations; d0 preloaded.
__device__ __forceinline__ void proc4(
    const float* __restrict__ det, size_t c0base, int loc, int Wm1, int log2W,
    size_t HW, float stride, float x1, float y1, float x2, float y2,
    float bcx, float bcy, float4 d0,
    float& conf, float& ciou, int& np, unsigned long long& pk)
{
    const int xi = loc & Wm1;
    const int yi = loc >> log2W;
    const float cy = ((float)yi + 0.5f) * stride;

    float cxs[4]; bool inb[4]; bool anyb = false;
    #pragma unroll
    for (int j = 0; j < 4; ++j) {
        cxs[j] = ((float)(xi + j) + 0.5f) * stride;
        inb[j] = (cxs[j] > x1) & (cxs[j] < x2) & (cy > y1) & (cy < y2);
        anyb |= inb[j];
    }

    const float zs[4] = { d0.x, d0.y, d0.z, d0.w };
    #pragma unroll
    for (int j = 0; j < 4; ++j) {
        const float z  = zs[j];
        const float e  = __expf(-fabsf(z));            // (0, 1]
        const float ce = fmaxf(z, 0.f) - (inb[j] ? z : 0.f) + __logf(1.f + e);
        const float inv = rcpf(1.f + e);
        const float p  = (z >= 0.f) ? inv : e * inv;   // sigmoid(z)
        const float pt = inb[j] ? p : 1.f - p;
        const float at = inb[j] ? 0.25f : 0.75f;
        const float om = 1.f - pt;
        conf += at * om * om * ce;
    }

    if (__any(anyb)) {  // wave-uniform: ltrb channels only near boxes
        const float4 d1 = *(const float4*)(det + c0base + HW + (size_t)loc);
        const float4 d2 = *(const float4*)(det + c0base + 2 * HW + (size_t)loc);
        const float4 d3 = *(const float4*)(det + c0base + 3 * HW + (size_t)loc);
        const float4 d4 = *(const float4*)(det + c0base + 4 * HW + (size_t)loc);
        const float ls[4] = { d1.x, d1.y, d1.z, d1.w };
        const float ts[4] = { d2.x, d2.y, d2.z, d2.w };
        const float rs[4] = { d3.x, d3.y, d3.z, d3.w };
        const float bs[4] = { d4.x, d4.y, d4.z, d4.w };
        #pragma unroll
        for (int j = 0; j < 4; ++j) {
            if (!inb[j]) continue;
            const float cx = cxs[j];
            const float pl  = __expf(fminf(fmaxf(ls[j], -6.f), 6.f)) * stride;
            const float pt_ = __expf(fminf(fmaxf(ts[j], -6.f), 6.f)) * stride;
            const float pr  = __expf(fminf(fmaxf(rs[j], -6.f), 6.f)) * stride;
            const float pb  = __expf(fminf(fmaxf(bs[j], -6.f), 6.f)) * stride;
            const float gl  = cx - x1, gtl = cy - y1, gr = x2 - cx, gb = y2 - cy;
            const float pw = pl + pr, ph = pt_ + pb;
            const float gw = gl + gr, gh = gtl + gb;
            const float iw = fmaxf(fminf(pl, gl) + fminf(pr, gr), 0.f);
            const float ih = fmaxf(fminf(pt_, gtl) + fminf(pb, gb), 0.f);
            const float inter = iw * ih;
            const float uni   = pw * ph + gw * gh - inter + 1e-6f;
            const float iou   = inter * rcpf(uni);
            const float cw_ = fmaxf(pl, gl) + fmaxf(pr, gr);
            const float ch_ = fmaxf(pt_, gtl) + fmaxf(pb, gb);
            const float c2  = cw_ * cw_ + ch_ * ch_ + 1e-6f;
            const float dcx = 0.5f * (pr - pl) - 0.5f * (gr - gl);
            const float dcy = 0.5f * (pb - pt_) - 0.5f * (gb - gtl);
            const float rho2 = dcx * dcx + dcy * dcy;
            const float dv = atanf(gw * rcpf(gh + 1e-6f)) - atanf(pw * rcpf(ph + 1e-6f));
            const float v  = (4.f / (float)(M_PI * M_PI)) * dv * dv;
            const float alpha = v * rcpf(1.f - iou + v + 1e-6f);
            ciou += 1.f - iou + rho2 * rcpf(c2) + alpha * v;
            ++np;
            const float ddx = cx - bcx, ddy = cy - bcy;
            const float dist2 = ddx * ddx + ddy * ddy;
            const unsigned long long cand =
                ((unsigned long long)__float_as_uint(dist2) << 32) | (unsigned)(loc + j);
            pk = cand < pk ? cand : pk;  // min -> first-index tie-break (argmin)
        }
    }
}

// Block map (256 threads, 4 locs per vec, stripes of 1024 locs):
//   bid < 512 : lvl0, b = bid>>2, base = (bid&3)*4096, 4 stripes -> partials
//   512..639  : lvl1, b = bid-512, 4 stripes, slot-owned -> finalized here
//   640..767  : lvl2, b = bid-640, 1 stripe,  slot-owned -> finalized here
__global__ __launch_bounds__(256) void level_k(
    const float* __restrict__ det8, const float* __restrict__ det16, const float* __restrict__ det32,
    const float* __restrict__ q16, const float* __restrict__ q32,
    const float* __restrict__ gtb, const float* __restrict__ gtq,
    unsigned long long* __restrict__ pk_p, float* __restrict__ conf_part,
    float* __restrict__ ciou_p, int* __restrict__ np_p,
    float* __restrict__ bbox_c, float* __restrict__ qual_c, int* __restrict__ npf)
{
    const int tid = (int)threadIdx.x;
    const int bid = (int)blockIdx.x;

    int b, base, log2W, nstripe;
    const float* det; float stride; float inv_denom; size_t HW;
    if (bid < 512) {
        b = bid >> 2; base = (bid & 3) * 4096; nstripe = 4;
        det = det8;  stride = 8.f;  log2W = 7; HW = 16384; inv_denom = 1.f / 2097152.f;
    } else if (bid < 640) {
        b = bid - 512; base = 0; nstripe = 4;
        det = det16; stride = 16.f; log2W = 6; HW = 4096; inv_denom = 1.f / 524288.f;
    } else {
        b = bid - 640; base = 0; nstripe = 1;
        det = det32; stride = 32.f; log2W = 5; HW = 1024; inv_denom = 1.f / 131072.f;
    }

    float conf = 0.f, ciou = 0.f; int np = 0;
    unsigned long long pk = ~0ULL;

    const float x1 = gtb[b * 4 + 0];
    if (x1 >= 0.f) {  // invalid batch contributes exactly 0 everywhere
        const float y1 = gtb[b * 4 + 1];
        const float x2 = gtb[b * 4 + 2];
        const float y2 = gtb[b * 4 + 3];
        const float bcx = 0.5f * (x1 + x2);
        const float bcy = 0.5f * (y1 + y2);
        const size_t c0base = (size_t)(b * 5) * HW;
        const int Wm1 = (1 << log2W) - 1;
        const int loc0 = base + (tid << 2);

        if (nstripe == 4) {
            // issue all 4 d0 loads before any dependent math (4x MLP)
            const float4 dA = *(const float4*)(det + c0base + (size_t)loc0);
            const float4 dB = *(const float4*)(det + c0base + (size_t)(loc0 + 1024));
            const float4 dC = *(const float4*)(det + c0base + (size_t)(loc0 + 2048));
            const float4 dD = *(const float4*)(det + c0base + (size_t)(loc0 + 3072));
            proc4(det, c0base, loc0,        Wm1, log2W, HW, stride, x1, y1, x2, y2, bcx, bcy, dA, conf, ciou, np, pk);
            proc4(det, c0base, loc0 + 1024, Wm1, log2W, HW, stride, x1, y1, x2, y2, bcx, bcy, dB, conf, ciou, np, pk);
            proc4(det, c0base, loc0 + 2048, Wm1, log2W, HW, stride, x1, y1, x2, y2, bcx, bcy, dC, conf, ciou, np, pk);
            proc4(det, c0base, loc0 + 3072, Wm1, log2W, HW, stride, x1, y1, x2, y2, bcx, bcy, dD, conf, ciou, np, pk);
        } else {
            const float4 dA = *(const float4*)(det + c0base + (size_t)loc0);
            proc4(det, c0base, loc0, Wm1, log2W, HW, stride, x1, y1, x2, y2, bcx, bcy, dA, conf, ciou, np, pk);
        }
        conf *= inv_denom;
    }

    // wave (64-lane) shuffle reduction
    #pragma unroll
    for (int off = 32; off > 0; off >>= 1) {
        conf += __shfl_down(conf, off);
        ciou += __shfl_down(ciou, off);
        np   += __shfl_down(np, off);
        unsigned long long o = __shfl_down(pk, off);
        pk = o < pk ? o : pk;
    }

    // cross-wave via LDS, plain stores only
    __shared__ float s_conf[4], s_ciou[4];
    __shared__ int   s_np[4];
    __shared__ unsigned long long s_pk[4];
    const int wid = tid >> 6;
    if ((tid & 63) == 0) {
        s_conf[wid] = conf; s_ciou[wid] = ciou; s_np[wid] = np; s_pk[wid] = pk;
    }
    __syncthreads();
    if (tid == 0) {
        conf_part[bid] = s_conf[0] + s_conf[1] + s_conf[2] + s_conf[3];
        const float ci = s_ciou[0] + s_ciou[1] + s_ciou[2] + s_ciou[3];
        const int   nt = s_np[0] + s_np[1] + s_np[2] + s_np[3];
        unsigned long long mn = s_pk[0];
        mn = s_pk[1] < mn ? s_pk[1] : mn;
        mn = s_pk[2] < mn ? s_pk[2] : mn;
        mn = s_pk[3] < mn ? s_pk[3] : mn;
        if (bid < 512) {            // lvl0: 4 blocks/slot -> partials
            ciou_p[bid] = ci; np_p[bid] = nt; pk_p[bid] = mn;
        } else {                    // lvl1/lvl2: slot-owned -> finalize now
            const int e = bid - 512;     // 0..255
            float bbv = 0.f, qlv = 0.f; int flag = 0;
            if (nt > 0) {
                bbv = ci * rcpf((float)nt);
                const unsigned idx = (unsigned)(mn & 0xffffffffULL);
                const float* q = (bid < 640) ? q16 : q32;
                const int l2  = (bid < 640) ? 12 : 10;
                float s = 0.f;
                #pragma unroll
                for (int c = 0; c < 4; ++c) {
                    const float best = q[((size_t)(b * 4 + c) << l2) + idx];
                    const float qt = fminf(fmaxf(gtq[b * 4 + c], 0.05f), 0.95f);
                    s -= qt * logsigf(best) + (1.f - qt) * logsigf(-best);
                }
                qlv = 0.25f * s;
                flag = 1;
            }
            bbox_c[e] = bbv; qual_c[e] = qlv; npf[e] = flag;
        }
    }
}

__global__ __launch_bounds__(512) void fin_k(
    const float* __restrict__ q8, const float* __restrict__ gtq,
    const unsigned long long* __restrict__ pk_p, const float* __restrict__ conf_part,
    const float* __restrict__ ciou_p, const int* __restrict__ np_p,
    const float* __restrict__ bbox_c, const float* __restrict__ qual_c,
    const int* __restrict__ npf,
    float* __restrict__ out)
{
    const int i = threadIdx.x;

    float cacc = conf_part[i] + (i < 256 ? conf_part[512 + i] : 0.f);

    float bb = 0.f, ql = 0.f; int n = 0;
    if (i < 128) {
        // lvl0 slot i: combine 4 block partials, gather + BCE
        const int f = i * 4;
        float ci = ciou_p[f] + ciou_p[f + 1] + ciou_p[f + 2] + ciou_p[f + 3];
        int   np = np_p[f] + np_p[f + 1] + np_p[f + 2] + np_p[f + 3];
        unsigned long long mn = pk_p[f];
        mn = pk_p[f + 1] < mn ? pk_p[f + 1] : mn;
        mn = pk_p[f + 2] < mn ? pk_p[f + 2] : mn;
        mn = pk_p[f + 3] < mn ? pk_p[f + 3] : mn;
        if (np > 0) {
            bb = ci * rcpf((float)np);
            const unsigned idx = (unsigned)(mn & 0xffffffffULL);
            float s = 0.f;
            #pragma unroll
            for (int c = 0; c < 4; ++c) {
                const float best = q8[((size_t)(i * 4 + c) << 14) + idx];
                const float qt = fminf(fmaxf(gtq[i * 4 + c], 0.05f), 0.95f);
                s -= qt * logsigf(best) + (1.f - qt) * logsigf(-best);
            }
            ql = 0.25f * s;
            n = 1;
        }
    } else if (i < 384) {
        // lvl1/lvl2 precomputed contributions (flat sum)
        const int e = i - 128;      // 0..255
        bb = bbox_c[e]; ql = qual_c[e]; n = npf[e];
    }

    // wave shuffle reduce, then one LDS round
    #pragma unroll
    for (int off = 32; off > 0; off >>= 1) {
        cacc += __shfl_down(cacc, off);
        bb   += __shfl_down(bb, off);
        ql   += __shfl_down(ql, off);
        n    += __shfl_down(n, off);
    }
    __shared__ float wc[8], wb[8], wq[8];
    __shared__ int   wn[8];
    if ((i & 63) == 0) { wc[i >> 6] = cacc; wb[i >> 6] = bb; wq[i >> 6] = ql; wn[i >> 6] = n; }
    __syncthreads();
    if (i == 0) {
        float conf_t = 0.f, tb0 = 0.f, tq0 = 0.f; int ntot = 0;
        #pragma unroll
        for (int w = 0; w < 8; ++w) { conf_t += wc[w]; tb0 += wb[w]; tq0 += wq[w]; ntot += wn[w]; }
        const float denom = fmaxf((float)ntot, 1.f);
        const float tb = (ntot > 0) ? tb0 / denom : tb0;
        const float tq = (ntot > 0) ? tq0 / denom : tq0;
        out[0] = conf_t + 5.f * tb + 0.05f * tq;
        out[1] = conf_t;
        out[2] = tb;
        out[3] = tq;
    }
}

extern "C" void kernel_launch(void* const* d_in, const int* in_sizes, int n_in,
                              void* d_out, int out_size, void* d_ws, size_t ws_size,
                              hipStream_t stream) {
    const float* det8  = (const float*)d_in[0];
    const float* det16 = (const float*)d_in[1];
    const float* det32 = (const float*)d_in[2];
    const float* q8    = (const float*)d_in[3];
    const float* q16   = (const float*)d_in[4];
    const float* q32   = (const float*)d_in[5];
    const float* gtb   = (const float*)d_in[6];
    const float* gtq   = (const float*)d_in[7];
    float* out = (float*)d_out;

    // workspace layout (14336 bytes): u64 first for alignment
    unsigned long long* pk_p = (unsigned long long*)d_ws;           // 512*8 = 4096
    float* conf_part = (float*)((char*)d_ws + 4096);                // 768*4 = 3072
    float* ciou_p    = (float*)((char*)d_ws + 7168);                // 512*4 = 2048
    int*   np_p      = (int*)((char*)d_ws + 9216);                  // 512*4 = 2048
    float* bbox_c    = (float*)((char*)d_ws + 11264);               // 256*4 = 1024
    float* qual_c    = (float*)((char*)d_ws + 12288);               // 256*4 = 1024
    int*   npf       = (int*)((char*)d_ws + 13312);                 // 256*4 = 1024

    hipLaunchKernelGGL(level_k, dim3(NBLK), dim3(256), 0, stream,
                       det8, det16, det32, q16, q32, gtb, gtq,
                       pk_p, conf_part, ciou_p, np_p, bbox_c, qual_c, npf);
    hipLaunchKernelGGL(fin_k, dim3(1), dim3(512), 0, stream,
                       q8, gtq, pk_p, conf_part, ciou_p, np_p, bbox_c, qual_c, npf, out);
}